// Round 12
// baseline (137.009 us; speedup 1.0000x reference)
//
#include <hip/hip_runtime.h>

namespace {

typedef float f32x4 __attribute__((ext_vector_type(4)));
typedef short bf16x8 __attribute__((ext_vector_type(8)));

constexpr int Bn = 64, QN = 16, Dn = 64, DVn = 64, KVn = 16384;
constexpr int SPLITS  = 4;
constexpr int TILE    = 64;                     // keys per tile
constexpr int THREADS = 256;                    // 4 waves
constexpr int NT      = KVn / (SPLITS * TILE);  // 64 tiles per block
constexpr int NSLOT   = 3;                      // K/V ring depth
constexpr int AP      = 68;                     // a_s row pitch: 272B = 17*16B

constexpr float SCALE = 0.125f * 1.4426950408889634f;  // 1/sqrt(64) * log2(e)

__device__ __forceinline__ unsigned cvt_pk_bf16(float a, float b) {
    unsigned r;
    asm("v_cvt_pk_bf16_f32 %0, %1, %2" : "=v"(r) : "v"(a), "v"(b));
    return r;
}

union FragU { unsigned u[4]; bf16x8 v; };

// split 8 fp32 into hi/lo bf16x8 fragments (hi = rne-bf16, lo = bf16(x - hi))
__device__ __forceinline__ void split8(const float* x, bf16x8& hi, bf16x8& lo) {
    FragU uh, ul;
#pragma unroll
    for (int p = 0; p < 4; ++p) {
        const float a = x[2 * p], b2 = x[2 * p + 1];
        const unsigned h = cvt_pk_bf16(a, b2);
        uh.u[p] = h;
        const float ha = __uint_as_float(h << 16);
        const float hb = __uint_as_float(h & 0xffff0000u);
        ul.u[p] = cvt_pk_bf16(a - ha, b2 - hb);
    }
    hi = uh.v; lo = ul.v;
}

// async 16B/lane global->LDS DMA: dest = wave-uniform base + lane*16
__device__ __forceinline__ void gl_lds16(const float* g, float* l) {
    __builtin_amdgcn_global_load_lds(
        (const __attribute__((address_space(1))) unsigned int*)g,
        (__attribute__((address_space(3))) unsigned int*)l,
        16, 0, 0);
}

__global__ __launch_bounds__(THREADS, 1)
void inv_attn_part(const float* __restrict__ query,
                   const float* __restrict__ key,
                   const float* __restrict__ value,
                   float* __restrict__ pout,   // [B][SPLITS][QN][DVn]
                   float* __restrict__ pden)   // [B][SPLITS][QN]
{
    // 3-slot ring, raw fp32, staged by global_load_lds. Chunk swizzle (16B
    // units): LDS chunk c of row r holds logical chunk c^(r&7), applied on
    // the GLOBAL SOURCE (linear dest + pre-swz src + swz read; r11-validated).
    __shared__ __align__(16) float kbuf[NSLOT][TILE * Dn];    // 3 x 16 KB
    __shared__ __align__(16) float vbuf[NSLOT][TILE * DVn];   // 3 x 16 KB
    __shared__ __align__(16) float a_s[QN * AP];              // 4.35 KB
    __shared__ float den_buf[4][QN];

    const int tid  = threadIdx.x;
    const int lane = tid & 63;
    const int w    = tid >> 6;          // wave: keys w*16.. (QK) / dv w*16.. (PV)
    const int l15  = lane & 15;
    const int g    = lane >> 4;
    const int spl  = blockIdx.x;
    const int b    = blockIdx.y;
    const int kt0  = spl * NT * TILE;

    // ---- hoist Q fragments (A-frag row=l15=q, k=ks*32+g*8+j; validated) ----
    bf16x8 qhi[2], qlo[2];
    {
        const float* qp = query + ((size_t)b * QN + l15) * Dn + g * 8;
#pragma unroll
        for (int ks = 0; ks < 2; ++ks) {
            const float4 u0 = *reinterpret_cast<const float4*>(qp + ks * 32);
            const float4 u1 = *reinterpret_cast<const float4*>(qp + ks * 32 + 4);
            float x[8] = {u0.x * SCALE, u0.y * SCALE, u0.z * SCALE, u0.w * SCALE,
                          u1.x * SCALE, u1.y * SCALE, u1.z * SCALE, u1.w * SCALE};
            split8(x, qhi[ks], qlo[ks]);
        }
    }

    f32x4 oacc = {0.f, 0.f, 0.f, 0.f};   // O[q=g*4+r][dv=w*16+l15]
    float den0 = 0.f, den1 = 0.f, den2 = 0.f, den3 = 0.f;

    // staging map: wave w stages rows w*16..+15; instr i covers rows
    // w*16+i*4+(lane>>4), dest chunk lane&15, src chunk pre-swizzled.
    const int srow   = lane >> 4;
    const int schunk = lane & 15;
    const float* kg = key   + ((size_t)b * KVn + kt0) * Dn;
    const float* vg = value + ((size_t)b * KVn + kt0) * Dn;

    auto issue_tile = [&](int t, int slot) {
#pragma unroll
        for (int i = 0; i < 4; ++i) {
            const int r  = w * 16 + i * 4 + srow;        // row in tile
            const int sc = schunk ^ (r & 7);             // pre-swizzled src chunk
            const size_t off = (size_t)(t * TILE + r) * Dn + sc * 4;
            gl_lds16(kg + off, &kbuf[slot][(w * 16 + i * 4) * Dn]);
            gl_lds16(vg + off, &vbuf[slot][(w * 16 + i * 4) * DVn]);
        }
    };

    // ---- prologue: 2 tiles in flight ----
    issue_tile(0, 0);
    issue_tile(1, 1);

    for (int t = 0; t < NT; ++t) {
        const int slot = t % NSLOT;

        // B1: tile t resident. COUNTED wait — tile t+1's 8 DMAs stay in
        // flight across the barrier (never vmcnt(0) until the last tile).
        if (t + 1 < NT) asm volatile("s_waitcnt vmcnt(8)" ::: "memory");
        else            asm volatile("s_waitcnt vmcnt(0)" ::: "memory");
        __builtin_amdgcn_s_barrier();
        __builtin_amdgcn_sched_barrier(0);

        // issue tile t+2 into slot (t+2)%3: safe, all PV(t-1) reads of that
        // slot completed before B1; stays in flight through QK+SM+PV+next B1.
        if (t + 2 < NT) issue_tile(t + 2, (t + 2) % NSLOT);

        // ---- QK^T from kbuf[slot] (swizzled b128 reads; hi/lo, 6 MFMA) ----
        const int rq = w * 16 + l15;       // this lane's key row
        const int sw = rq & 7;
        f32x4 sacc = {0.f, 0.f, 0.f, 0.f};
#pragma unroll
        for (int ks = 0; ks < 2; ++ks) {
            const int c0 = ks * 8 + g * 2;
            const f32x4 r0 = *reinterpret_cast<const f32x4*>(
                &kbuf[slot][rq * Dn + ((c0    ) ^ sw) * 4]);
            const f32x4 r1 = *reinterpret_cast<const f32x4*>(
                &kbuf[slot][rq * Dn + ((c0 + 1) ^ sw) * 4]);
            float x[8] = {r0[0], r0[1], r0[2], r0[3], r1[0], r1[1], r1[2], r1[3]};
            bf16x8 khi, klo;
            split8(x, khi, klo);
            sacc = __builtin_amdgcn_mfma_f32_16x16x32_bf16(qhi[ks], khi, sacc, 0, 0, 0);
            sacc = __builtin_amdgcn_mfma_f32_16x16x32_bf16(qhi[ks], klo, sacc, 0, 0, 0);
            sacc = __builtin_amdgcn_mfma_f32_16x16x32_bf16(qlo[ks], khi, sacc, 0, 0, 0);
        }

        // ---- softmax over q (16) at key = kt0 + t*64 + rq (validated) ----
        float m = fmaxf(fmaxf(sacc[0], sacc[1]), fmaxf(sacc[2], sacc[3]));
        m = fmaxf(m, __shfl_xor(m, 16, 64));
        m = fmaxf(m, __shfl_xor(m, 32, 64));
        float p0 = exp2f(sacc[0] - m), p1 = exp2f(sacc[1] - m);
        float p2 = exp2f(sacc[2] - m), p3 = exp2f(sacc[3] - m);
        float s4 = p0 + p1 + p2 + p3;
        s4 += __shfl_xor(s4, 16, 64);
        s4 += __shfl_xor(s4, 32, 64);
        const float inv = 1.0f / s4;
        p0 *= inv; p1 *= inv; p2 *= inv; p3 *= inv;
        a_s[(g * 4 + 0) * AP + rq] = p0;
        a_s[(g * 4 + 1) * AP + rq] = p1;
        a_s[(g * 4 + 2) * AP + rq] = p2;
        a_s[(g * 4 + 3) * AP + rq] = p3;
        den0 += p0; den1 += p1; den2 += p2; den3 += p3;

        // B2: publish a_s. LGKM-only wait — the DMA queue (vmcnt) is NOT
        // drained here; tile t+1/t+2 loads keep flying.
        asm volatile("s_waitcnt lgkmcnt(0)" ::: "memory");
        __builtin_amdgcn_s_barrier();
        __builtin_amdgcn_sched_barrier(0);

        // ---- PV: O[q][dv] += P[q][key]*V[key][dv]; V from fp32 LDS ----
        // (single a_s buffer is safe: next write is after next B1)
        const int dv = w * 16 + l15;
        const int ch = dv >> 2, wrd = dv & 3;
#pragma unroll
        for (int ks = 0; ks < 2; ++ks) {
            const int base = ks * 32 + g * 8;
            const float4 a0 = *reinterpret_cast<const float4*>(&a_s[l15 * AP + base]);
            const float4 a1 = *reinterpret_cast<const float4*>(&a_s[l15 * AP + base + 4]);
            FragU ua;
            ua.u[0] = cvt_pk_bf16(a0.x, a0.y);
            ua.u[1] = cvt_pk_bf16(a0.z, a0.w);
            ua.u[2] = cvt_pk_bf16(a1.x, a1.y);
            ua.u[3] = cvt_pk_bf16(a1.z, a1.w);
            float vx[8];
#pragma unroll
            for (int j = 0; j < 8; ++j) {
                const int k = base + j;                 // k&7 == j
                vx[j] = vbuf[slot][k * DVn + ((ch ^ j) << 2) + wrd];
            }
            FragU uv;
            uv.u[0] = cvt_pk_bf16(vx[0], vx[1]);
            uv.u[1] = cvt_pk_bf16(vx[2], vx[3]);
            uv.u[2] = cvt_pk_bf16(vx[4], vx[5]);
            uv.u[3] = cvt_pk_bf16(vx[6], vx[7]);
            oacc = __builtin_amdgcn_mfma_f32_16x16x32_bf16(ua.v, uv.v, oacc, 0, 0, 0);
        }
    }

    // ---- write partial outputs: O[q=g*4+r][dv=w*16+l15] ----
    const size_t obase = (((size_t)b * SPLITS + spl) * QN) * DVn;
    const int dvo = w * 16 + l15;
    pout[obase + (g * 4 + 0) * DVn + dvo] = oacc[0];
    pout[obase + (g * 4 + 1) * DVn + dvo] = oacc[1];
    pout[obase + (g * 4 + 2) * DVn + dvo] = oacc[2];
    pout[obase + (g * 4 + 3) * DVn + dvo] = oacc[3];

    // ---- denominator: reduce over the 16 keys (l15) within the wave ----
#pragma unroll
    for (int off = 1; off < 16; off <<= 1) {
        den0 += __shfl_xor(den0, off, 64);
        den1 += __shfl_xor(den1, off, 64);
        den2 += __shfl_xor(den2, off, 64);
        den3 += __shfl_xor(den3, off, 64);
    }
    if (l15 == 0) {
        den_buf[w][g * 4 + 0] = den0;
        den_buf[w][g * 4 + 1] = den1;
        den_buf[w][g * 4 + 2] = den2;
        den_buf[w][g * 4 + 3] = den3;
    }
    __syncthreads();   // outside the hot loop: full drain acceptable
    if (tid < QN) {
        const float d = den_buf[0][tid] + den_buf[1][tid] + den_buf[2][tid] + den_buf[3][tid];
        pden[((size_t)b * SPLITS + spl) * QN + tid] = d;
    }
}

__global__ __launch_bounds__(256)
void inv_attn_reduce(const float* __restrict__ pout,
                     const float* __restrict__ pden,
                     float* __restrict__ out)
{
    const int gid = blockIdx.x * blockDim.x + threadIdx.x;   // 0..65535
    const int dv = gid & 63;
    const int q  = (gid >> 6) & (QN - 1);
    const int b  = gid >> 10;
    float sum = 0.f, den = 0.f;
#pragma unroll
    for (int sp = 0; sp < SPLITS; ++sp) {
        sum += pout[(((size_t)b * SPLITS + sp) * QN + q) * DVn + dv];
        den += pden[((size_t)b * SPLITS + sp) * QN + q];
    }
    out[gid] = sum / (den + 1e-8f);
}

}  // namespace

extern "C" void kernel_launch(void* const* d_in, const int* in_sizes, int n_in,
                              void* d_out, int out_size, void* d_ws, size_t ws_size,
                              hipStream_t stream) {
    const float* query = (const float*)d_in[0];
    const float* key   = (const float*)d_in[1];
    const float* value = (const float*)d_in[2];
    float* out = (float*)d_out;

    float* pout = (float*)d_ws;                               // 1.0 MB
    float* pden = pout + (size_t)Bn * SPLITS * QN * DVn;      // 16 KB

    dim3 grid1(SPLITS, Bn);   // 256 blocks = 1/CU, single residency round
    inv_attn_part<<<grid1, THREADS, 0, stream>>>(query, key, value, pout, pden);

    const int total = Bn * QN * DVn;   // 65536
    inv_attn_reduce<<<total / 256, 256, 0, stream>>>(pout, pden, out);
}

// Round 13
// 102.929 us; speedup vs baseline: 1.3311x; 1.3311x over previous
//
#include <hip/hip_runtime.h>

namespace {

typedef float f32x4 __attribute__((ext_vector_type(4)));
typedef short bf16x8 __attribute__((ext_vector_type(8)));

constexpr int Bn = 64, QN = 16, Dn = 64, DVn = 64, KVn = 16384;
constexpr int SPLITS  = 8;
constexpr int TILE    = 64;                     // keys per tile
constexpr int THREADS = 256;                    // 4 waves
constexpr int NT      = KVn / (SPLITS * TILE);  // 32 tiles per block
constexpr int AP      = 68;                     // a_s row pitch: 272B = 17*16B

constexpr float SCALE = 0.125f * 1.4426950408889634f;  // 1/sqrt(64) * log2(e)

__device__ __forceinline__ unsigned cvt_pk_bf16(float a, float b) {
    unsigned r;
    asm("v_cvt_pk_bf16_f32 %0, %1, %2" : "=v"(r) : "v"(a), "v"(b));
    return r;
}

union FragU { unsigned u[4]; bf16x8 v; };

// split 8 fp32 into hi/lo bf16x8 fragments (hi = rne-bf16, lo = bf16(x - hi))
__device__ __forceinline__ void split8(const float* x, bf16x8& hi, bf16x8& lo) {
    FragU uh, ul;
#pragma unroll
    for (int p = 0; p < 4; ++p) {
        const float a = x[2 * p], b2 = x[2 * p + 1];
        const unsigned h = cvt_pk_bf16(a, b2);
        uh.u[p] = h;
        const float ha = __uint_as_float(h << 16);
        const float hb = __uint_as_float(h & 0xffff0000u);
        ul.u[p] = cvt_pk_bf16(a - ha, b2 - hb);
    }
    hi = uh.v; lo = ul.v;
}

// async 16B/lane global->LDS DMA: dest = wave-uniform base + lane*16,
// src = per-lane global address (r7-validated helper).
__device__ __forceinline__ void gl_lds16(const float* g, float* l) {
    __builtin_amdgcn_global_load_lds(
        (const __attribute__((address_space(1))) unsigned int*)g,
        (__attribute__((address_space(3))) unsigned int*)l,
        16, 0, 0);
}

__global__ __launch_bounds__(THREADS, 2)
void inv_attn_part(const float* __restrict__ query,
                   const float* __restrict__ key,
                   const float* __restrict__ value,
                   float* __restrict__ pout,   // [B][SPLITS][QN][DVn]
                   float* __restrict__ pden)   // [B][SPLITS][QN]
{
    // K/V tiles staged RAW fp32 by global_load_lds, double-buffered.
    // Chunk swizzle (16B units): LDS chunk c of row r holds logical chunk
    // c ^ (r&7); applied on the GLOBAL SOURCE (rule: linear dest + pre-swz
    // src + swz read).
    __shared__ __align__(16) float kbuf[2][TILE * Dn];    // 2 x 16 KB
    __shared__ __align__(16) float vbuf[2][TILE * DVn];   // 2 x 16 KB
    __shared__ __align__(16) float a_s[2][QN * AP];       // 2 x 4.35 KB
    __shared__ float den_buf[4][QN];

    const int tid  = threadIdx.x;
    const int lane = tid & 63;
    const int w    = tid >> 6;          // wave: keys w*16.. (QK) / dv w*16.. (PV)
    const int l15  = lane & 15;
    const int g    = lane >> 4;
    const int spl  = blockIdx.x;
    const int b    = blockIdx.y;
    const int kt0  = spl * NT * TILE;

    // ---- hoist Q fragments (A-frag row=l15=q, k=ks*32+g*8+j; validated) ----
    bf16x8 qhi[2], qlo[2];
    {
        const float* qp = query + ((size_t)b * QN + l15) * Dn + g * 8;
#pragma unroll
        for (int ks = 0; ks < 2; ++ks) {
            const float4 u0 = *reinterpret_cast<const float4*>(qp + ks * 32);
            const float4 u1 = *reinterpret_cast<const float4*>(qp + ks * 32 + 4);
            float x[8] = {u0.x * SCALE, u0.y * SCALE, u0.z * SCALE, u0.w * SCALE,
                          u1.x * SCALE, u1.y * SCALE, u1.z * SCALE, u1.w * SCALE};
            split8(x, qhi[ks], qlo[ks]);
        }
    }

    f32x4 oacc = {0.f, 0.f, 0.f, 0.f};   // O[q=g*4+r][dv=w*16+l15]
    float den0 = 0.f, den1 = 0.f, den2 = 0.f, den3 = 0.f;

    // staging map: wave w stages rows w*16..+15; instr i covers rows
    // w*16+i*4 + (lane>>4), dest chunk lane&15, src chunk pre-swizzled.
    const int srow   = lane >> 4;
    const int schunk = lane & 15;
    const float* kg = key   + ((size_t)b * KVn + kt0) * Dn;
    const float* vg = value + ((size_t)b * KVn + kt0) * Dn;

    auto issue_tile = [&](int t, int buf) {
#pragma unroll
        for (int i = 0; i < 4; ++i) {
            const int r  = w * 16 + i * 4 + srow;        // row in tile
            const int sc = schunk ^ (r & 7);             // pre-swizzled src chunk
            const size_t off = (size_t)(t * TILE + r) * Dn + sc * 4;
            gl_lds16(kg + off, &kbuf[buf][(w * 16 + i * 4) * Dn]);
            gl_lds16(vg + off, &vbuf[buf][(w * 16 + i * 4) * DVn]);
        }
    };

    // ---- prologue: tile 0 in flight (drained by first barrier) ----
    issue_tile(0, 0);

    for (int t = 0; t < NT; ++t) {
        const int buf = t & 1;

        __syncthreads();   // B1: tile t staged+visible; all PV(t-1) reads done

        // issue tile t+1 into the other buffer; drains at B2 (QK+softmax
        // window hides most of the load latency; non-sinkable by compiler)
        if (t + 1 < NT) issue_tile(t + 1, buf ^ 1);

        // ---- QK^T from kbuf (swizzled b128 reads; hi/lo split, 6 MFMA) ----
        const int rq = w * 16 + l15;       // this lane's key row
        const int sw = rq & 7;
        f32x4 sacc = {0.f, 0.f, 0.f, 0.f};
#pragma unroll
        for (int ks = 0; ks < 2; ++ks) {
            const int c0 = ks * 8 + g * 2;
            const f32x4 r0 = *reinterpret_cast<const f32x4*>(
                &kbuf[buf][rq * Dn + ((c0    ) ^ sw) * 4]);
            const f32x4 r1 = *reinterpret_cast<const f32x4*>(
                &kbuf[buf][rq * Dn + ((c0 + 1) ^ sw) * 4]);
            float x[8] = {r0[0], r0[1], r0[2], r0[3], r1[0], r1[1], r1[2], r1[3]};
            bf16x8 khi, klo;
            split8(x, khi, klo);
            sacc = __builtin_amdgcn_mfma_f32_16x16x32_bf16(qhi[ks], khi, sacc, 0, 0, 0);
            sacc = __builtin_amdgcn_mfma_f32_16x16x32_bf16(qhi[ks], klo, sacc, 0, 0, 0);
            sacc = __builtin_amdgcn_mfma_f32_16x16x32_bf16(qlo[ks], khi, sacc, 0, 0, 0);
        }

        // ---- softmax over q (16) at key = kt0 + t*64 + rq (validated) ----
        float m = fmaxf(fmaxf(sacc[0], sacc[1]), fmaxf(sacc[2], sacc[3]));
        m = fmaxf(m, __shfl_xor(m, 16, 64));
        m = fmaxf(m, __shfl_xor(m, 32, 64));
        float p0 = exp2f(sacc[0] - m), p1 = exp2f(sacc[1] - m);
        float p2 = exp2f(sacc[2] - m), p3 = exp2f(sacc[3] - m);
        float s4 = p0 + p1 + p2 + p3;
        s4 += __shfl_xor(s4, 16, 64);
        s4 += __shfl_xor(s4, 32, 64);
        const float inv = 1.0f / s4;
        p0 *= inv; p1 *= inv; p2 *= inv; p3 *= inv;
        a_s[buf][(g * 4 + 0) * AP + rq] = p0;
        a_s[buf][(g * 4 + 1) * AP + rq] = p1;
        a_s[buf][(g * 4 + 2) * AP + rq] = p2;
        a_s[buf][(g * 4 + 3) * AP + rq] = p3;
        den0 += p0; den1 += p1; den2 += p2; den3 += p3;

        __syncthreads();   // B2: publish a_s; drains tile t+1's staging

        // ---- PV: O[q][dv] += P[q][key] * V[key][dv]; V from fp32 LDS ----
        const int dv = w * 16 + l15;
        const int ch = dv >> 2, wrd = dv & 3;
#pragma unroll
        for (int ks = 0; ks < 2; ++ks) {
            const int base = ks * 32 + g * 8;
            const float4 a0 = *reinterpret_cast<const float4*>(&a_s[buf][l15 * AP + base]);
            const float4 a1 = *reinterpret_cast<const float4*>(&a_s[buf][l15 * AP + base + 4]);
            FragU ua;
            ua.u[0] = cvt_pk_bf16(a0.x, a0.y);
            ua.u[1] = cvt_pk_bf16(a0.z, a0.w);
            ua.u[2] = cvt_pk_bf16(a1.x, a1.y);
            ua.u[3] = cvt_pk_bf16(a1.z, a1.w);
            float vx[8];
#pragma unroll
            for (int j = 0; j < 8; ++j) {
                const int k = base + j;                 // k&7 == j
                vx[j] = vbuf[buf][k * DVn + ((ch ^ j) << 2) + wrd];
            }
            FragU uv;
            uv.u[0] = cvt_pk_bf16(vx[0], vx[1]);
            uv.u[1] = cvt_pk_bf16(vx[2], vx[3]);
            uv.u[2] = cvt_pk_bf16(vx[4], vx[5]);
            uv.u[3] = cvt_pk_bf16(vx[6], vx[7]);
            oacc = __builtin_amdgcn_mfma_f32_16x16x32_bf16(ua.v, uv.v, oacc, 0, 0, 0);
        }
    }

    // ---- write partial outputs: O[q=g*4+r][dv=w*16+l15] ----
    const size_t obase = (((size_t)b * SPLITS + spl) * QN) * DVn;
    const int dvo = w * 16 + l15;
    pout[obase + (g * 4 + 0) * DVn + dvo] = oacc[0];
    pout[obase + (g * 4 + 1) * DVn + dvo] = oacc[1];
    pout[obase + (g * 4 + 2) * DVn + dvo] = oacc[2];
    pout[obase + (g * 4 + 3) * DVn + dvo] = oacc[3];

    // ---- denominator: reduce over the 16 keys (l15) within the wave ----
#pragma unroll
    for (int off = 1; off < 16; off <<= 1) {
        den0 += __shfl_xor(den0, off, 64);
        den1 += __shfl_xor(den1, off, 64);
        den2 += __shfl_xor(den2, off, 64);
        den3 += __shfl_xor(den3, off, 64);
    }
    if (l15 == 0) {
        den_buf[w][g * 4 + 0] = den0;
        den_buf[w][g * 4 + 1] = den1;
        den_buf[w][g * 4 + 2] = den2;
        den_buf[w][g * 4 + 3] = den3;
    }
    __syncthreads();
    if (tid < QN) {
        const float d = den_buf[0][tid] + den_buf[1][tid] + den_buf[2][tid] + den_buf[3][tid];
        pden[((size_t)b * SPLITS + spl) * QN + tid] = d;
    }
}

__global__ __launch_bounds__(256)
void inv_attn_reduce(const float* __restrict__ pout,
                     const float* __restrict__ pden,
                     float* __restrict__ out)
{
    const int gid = blockIdx.x * blockDim.x + threadIdx.x;   // 0..65535
    const int dv = gid & 63;
    const int q  = (gid >> 6) & (QN - 1);
    const int b  = gid >> 10;
    float sum = 0.f, den = 0.f;
#pragma unroll 8
    for (int sp = 0; sp < SPLITS; ++sp) {
        sum += pout[(((size_t)b * SPLITS + sp) * QN + q) * DVn + dv];
        den += pden[((size_t)b * SPLITS + sp) * QN + q];
    }
    out[gid] = sum / (den + 1e-8f);
}

}  // namespace

extern "C" void kernel_launch(void* const* d_in, const int* in_sizes, int n_in,
                              void* d_out, int out_size, void* d_ws, size_t ws_size,
                              hipStream_t stream) {
    const float* query = (const float*)d_in[0];
    const float* key   = (const float*)d_in[1];
    const float* value = (const float*)d_in[2];
    float* out = (float*)d_out;

    // partials: 2.0 MB + 32 KB
    float* pout = (float*)d_ws;
    float* pden = pout + (size_t)Bn * SPLITS * QN * DVn;

    dim3 grid1(SPLITS, Bn);   // 512 blocks = 2/CU x 256 CU, single round
    inv_attn_part<<<grid1, THREADS, 0, stream>>>(query, key, value, pout, pden);

    const int total = Bn * QN * DVn;   // 65536
    inv_attn_reduce<<<total / 256, 256, 0, stream>>>(pout, pden, out);
}